// Round 9
// baseline (43.072 us; speedup 1.0000x reference)
//
#include <hip/hip_runtime.h>
#include <stdint.h>

#define B 512
#define D 128
#define HALFC 131072u
#define SUB 4
#define NSLOT (SUB * 4)
#define NPART (B * SUB)

__device__ __forceinline__ uint32_t rotl32(uint32_t x, uint32_t r) {
  return (x << r) | (x >> (32u - r));
}

// Exact JAX/XLA threefry2x32 (20 rounds, key-schedule injections every 4).
__device__ __forceinline__ void threefry2x32(uint32_t k0, uint32_t k1,
                                             uint32_t x0, uint32_t x1,
                                             uint32_t& y0, uint32_t& y1) {
  uint32_t k2 = k0 ^ k1 ^ 0x1BD11BDAu;
  x0 += k0; x1 += k1;
#define TF_R(r) { x0 += x1; x1 = rotl32(x1, r); x1 ^= x0; }
  TF_R(13) TF_R(15) TF_R(26) TF_R(6)
  x0 += k1; x1 += k2 + 1u;
  TF_R(17) TF_R(29) TF_R(16) TF_R(24)
  x0 += k2; x1 += k0 + 2u;
  TF_R(13) TF_R(15) TF_R(26) TF_R(6)
  x0 += k0; x1 += k1 + 3u;
  TF_R(17) TF_R(29) TF_R(16) TF_R(24)
  x0 += k1; x1 += k2 + 4u;
  TF_R(13) TF_R(15) TF_R(26) TF_R(6)
  x0 += k2; x1 += k0 + 5u;
#undef TF_R
  y0 = x0; y1 = x1;
}

// Two independent chains with INDEPENDENT KEYS (anchor A / anchor B).
__device__ __forceinline__ void threefry2x32_dual2(
    uint32_t ka0, uint32_t ka1, uint32_t kb0, uint32_t kb1,
    uint32_t a0, uint32_t a1, uint32_t b0, uint32_t b1,
    uint32_t& ya0, uint32_t& ya1, uint32_t& yb0, uint32_t& yb1) {
  uint32_t ka2 = ka0 ^ ka1 ^ 0x1BD11BDAu;
  uint32_t kb2 = kb0 ^ kb1 ^ 0x1BD11BDAu;
  a0 += ka0; a1 += ka1; b0 += kb0; b1 += kb1;
#define TF_R2(r) { a0 += a1; a1 = rotl32(a1, r); a1 ^= a0; \
                   b0 += b1; b1 = rotl32(b1, r); b1 ^= b0; }
  TF_R2(13) TF_R2(15) TF_R2(26) TF_R2(6)
  a0 += ka1; a1 += ka2 + 1u; b0 += kb1; b1 += kb2 + 1u;
  TF_R2(17) TF_R2(29) TF_R2(16) TF_R2(24)
  a0 += ka2; a1 += ka0 + 2u; b0 += kb2; b1 += kb0 + 2u;
  TF_R2(13) TF_R2(15) TF_R2(26) TF_R2(6)
  a0 += ka0; a1 += ka1 + 3u; b0 += kb0; b1 += kb1 + 3u;
  TF_R2(17) TF_R2(29) TF_R2(16) TF_R2(24)
  a0 += ka1; a1 += ka2 + 4u; b0 += kb1; b1 += kb2 + 4u;
  TF_R2(13) TF_R2(15) TF_R2(26) TF_R2(6)
  a0 += ka2; a1 += ka0 + 5u; b0 += kb2; b1 += kb0 + 5u;
#undef TF_R2
  ya0 = a0; ya1 = a1; yb0 = b0; yb1 = b1;
}

// K1: tiled dist "GEMM". Block (ti,tj) computes a 32x32 tile of dist from two
// coalesced-staged 32x128 LDS panels (fused sq). Block 0 also computes the
// 512 anchor keys.
__global__ __launch_bounds__(256) void dist_kernel(
    const float* __restrict__ emb, float* __restrict__ dist,
    uint32_t* __restrict__ keys0, uint32_t* __restrict__ keys1) {
  __shared__ float As[32][132];  // pad 132: bank = (4r + k) % 32, conflict-free
  __shared__ float Bs[32][132];
  __shared__ float sqa[32], sqb[32];
  int bid = blockIdx.x;
  int ti = bid >> 4, tj = bid & 15;
  int t = threadIdx.x;

  // coalesced stage: 32 rows x 128 floats = 1024 float4 per panel
  const float4* ga = reinterpret_cast<const float4*>(emb + (size_t)ti * 32 * D);
  const float4* gb = reinterpret_cast<const float4*>(emb + (size_t)tj * 32 * D);
  #pragma unroll
  for (int k = 0; k < 4; ++k) {
    int idx = t + k * 256;   // float4 index 0..1023
    int r = idx >> 5;        // 32 float4 per row
    int c4 = idx & 31;
    *reinterpret_cast<float4*>(&As[r][c4 * 4]) = ga[idx];
    *reinterpret_cast<float4*>(&Bs[r][c4 * 4]) = gb[idx];
  }
  __syncthreads();

  // fused sq: 64 rows (32 A + 32 B), 4 threads/row of 32 floats each
  {
    int row = t >> 2, seg = t & 3;
    const float* src = (row < 32) ? &As[row][seg * 32] : &Bs[row - 32][seg * 32];
    float s = 0.f;
    #pragma unroll
    for (int m = 0; m < 32; ++m) { float v = src[m]; s += v * v; }
    s += __shfl_xor(s, 1);
    s += __shfl_xor(s, 2);
    if (seg == 0) { if (row < 32) sqa[row] = s; else sqb[row - 32] = s; }
  }

  // dots: thread (r = t>>3, g = t&7) computes cols c = g + 8j, j=0..3
  int r = t >> 3, g = t & 7;
  const float4* A4 = reinterpret_cast<const float4*>(&As[r][0]);
  const float4* B0 = reinterpret_cast<const float4*>(&Bs[g][0]);
  const float4* B1 = reinterpret_cast<const float4*>(&Bs[g + 8][0]);
  const float4* B2 = reinterpret_cast<const float4*>(&Bs[g + 16][0]);
  const float4* B3 = reinterpret_cast<const float4*>(&Bs[g + 24][0]);
  float acc0 = 0.f, acc1 = 0.f, acc2 = 0.f, acc3 = 0.f;
  #pragma unroll 8
  for (int k4 = 0; k4 < 32; ++k4) {
    float4 a = A4[k4];
    float4 b0 = B0[k4], b1 = B1[k4], b2 = B2[k4], b3 = B3[k4];
    acc0 += a.x * b0.x + a.y * b0.y + a.z * b0.z + a.w * b0.w;
    acc1 += a.x * b1.x + a.y * b1.y + a.z * b1.z + a.w * b1.w;
    acc2 += a.x * b2.x + a.y * b2.y + a.z * b2.z + a.w * b2.w;
    acc3 += a.x * b3.x + a.y * b3.y + a.z * b3.z + a.w * b3.w;
  }
  __syncthreads();  // sqa/sqb ready
  float sa = sqa[r];
  float* drow = dist + (size_t)(ti * 32 + r) * B + tj * 32;
  drow[g]      = sqrtf(fmaxf(sa + sqb[g]      - 2.f * acc0, 0.f));
  drow[g + 8]  = sqrtf(fmaxf(sa + sqb[g + 8]  - 2.f * acc1, 0.f));
  drow[g + 16] = sqrtf(fmaxf(sa + sqb[g + 16] - 2.f * acc2, 0.f));
  drow[g + 24] = sqrtf(fmaxf(sa + sqb[g + 24] - 2.f * acc3, 0.f));

  // block 0 tail: anchor keys
  // keys[p] from split(key(42), 512): out[q] = q<512 ? y0(q,q+512) : y1(q-512,q)
  if (bid == 0) {
    #pragma unroll
    for (int pp = 0; pp < 2; ++pp) {
      int p = t + pp * 256;
      uint32_t i0 = 2u * (uint32_t)p, i1 = i0 + 1u;
      uint32_t a0, a1, b0, b1;
      if (p < 256) {
        threefry2x32(0u, 42u, i0, i0 + 512u, a0, a1);
        threefry2x32(0u, 42u, i1, i1 + 512u, b0, b1);
        keys0[p] = a0; keys1[p] = b0;
      } else {
        threefry2x32(0u, 42u, i0 - 512u, i0, a0, a1);
        threefry2x32(0u, 42u, i1 - 512u, i1, b0, b1);
        keys0[p] = a1; keys1[p] = b1;
      }
    }
  }
}

// K2 (row-major, anchor-paired): block = (row i, sub). Each wave iteration
// handles TWO anchors A,B: shared 8-round ballot compaction (2 masks/round),
// dual2-threefry with independent keys (chain A = A's candidates, chain B =
// B's), two packed-u32 lex argmax reduces. Invalid/self anchors use a
// pos_d=-2 sentinel (empty window), keeping everything branch-free.
__global__ __launch_bounds__(256) void triplet_kernel(
    const float* __restrict__ dist, const int* __restrict__ labels,
    const uint32_t* __restrict__ keys0, const uint32_t* __restrict__ keys1,
    double* __restrict__ partials, int* __restrict__ pcnt) {
  __shared__ float drow[B];
  __shared__ unsigned short slab[B];
  __shared__ unsigned short list_sh[B];
  __shared__ unsigned short cand[4][2][B];
  __shared__ int nlist_sh;
  __shared__ double lsum[4];
  __shared__ unsigned int lcnt[4];

  int bid = blockIdx.x;
  int i = bid >> 2;  // SUB = 4
  int sub = bid & 3;
  int t = threadIdx.x;
  slab[t] = (unsigned short)labels[t];
  slab[t + 256] = (unsigned short)labels[t + 256];
  const float* __restrict__ dg = dist + (size_t)i * B;
  drow[t] = dg[t];
  drow[t + 256] = dg[t + 256];
  __syncthreads();

  int wave = t >> 6, lane = t & 63;
  unsigned long long lmask_lt = (1ull << lane) - 1ull;
  unsigned short lab_i = slab[i];

  // wave 0: ascending list of same-label anchors p (includes i; masked later)
  if (wave == 0) {
    int n = 0;
    #pragma unroll
    for (int c = 0; c < 8; ++c) {
      int r = c * 64 + lane;
      bool v = (slab[r] == lab_i);
      unsigned long long mk = __ballot(v);
      if (v) list_sh[n + __popcll(mk & lmask_lt)] = (unsigned short)r;
      n += __popcll(mk);
    }
    if (lane == 0) nlist_sh = (n == B) ? 0 : n;  // n==B -> no negatives
  }

  // row-invariant per-lane data + in-block hard-negative argmin
  float dd8[8];
  uint32_t negm = 0;
  unsigned long long hkey = ~0ull;
  #pragma unroll
  for (int jc = 0; jc < 8; ++jc) {
    int j = jc * 64 + lane;
    dd8[jc] = drow[j];
    bool neg = (slab[j] != lab_i);
    negm |= (uint32_t)neg << jc;
    if (neg) {
      unsigned long long k =
          (((unsigned long long)__float_as_uint(dd8[jc])) << 9) | (unsigned)j;
      if (k < hkey) hkey = k;
    }
  }
  #pragma unroll
  for (int off = 32; off; off >>= 1) {
    unsigned long long o = __shfl_xor(hkey, off);
    if (o < hkey) hkey = o;
  }
  int hard = (int)(hkey & 0x1FFu);  // valid whenever any negative exists
  uint32_t rowbase = (uint32_t)((i & 255) * B);
  bool take_hi = (i >= 256);
  __syncthreads();  // list_sh / nlist_sh ready

  int nlist = nlist_sh;
  unsigned short* wcA = cand[wave][0];
  unsigned short* wcB = cand[wave][1];
  double wsum = 0.0;
  unsigned int wcnt = 0;

  for (int k = sub * 4 + wave; k < nlist; k += 2 * NSLOT) {
    int kB = k + NSLOT;
    int pA = list_sh[k];
    int pB = (kB < nlist) ? (int)list_sh[kB] : pA;
    pA = __builtin_amdgcn_readfirstlane(pA);
    pB = __builtin_amdgcn_readfirstlane(pB);
    bool vA = (pA != i);
    bool vB = (kB < nlist) && (pB != i);
    uint32_t kpA0 = keys0[pA], kpA1 = keys1[pA];
    uint32_t kpB0 = keys0[pB], kpB1 = keys1[pB];
    float pdA = vA ? drow[pA] : -2.0f;  // sentinel: window (-2,-1) is empty
    float pdB = vB ? drow[pB] : -2.0f;
    float hiA = pdA + 1.0f, hiB = pdB + 1.0f;  // margin = 1.0

    int ncA = 0, ncB = 0;
    #pragma unroll
    for (int jc = 0; jc < 8; ++jc) {
      float dd = dd8[jc];
      bool bn = (negm >> jc) & 1u;
      bool mA = bn && (dd > pdA) && (dd < hiA);
      bool mB = bn && (dd > pdB) && (dd < hiB);
      unsigned long long mkA = __ballot(mA);
      unsigned long long mkB = __ballot(mB);
      unsigned short jv = (unsigned short)(jc * 64 + lane);
      if (mA) wcA[ncA + __popcll(mkA & lmask_lt)] = jv;
      if (mB) wcB[ncB + __popcll(mkB & lmask_lt)] = jv;
      ncA += __popcll(mkA);
      ncB += __popcll(mkB);
    }

    int ncmax = ncA > ncB ? ncA : ncB;
    uint32_t bestA = 0u, bestB = 0u;
    for (int c = lane; c < ncmax; c += 64) {
      int jA = wcA[(c < ncA) ? c : 0];
      int jB = wcB[(c < ncB) ? c : 0];
      uint32_t ya0, ya1, yb0, yb1;
      threefry2x32_dual2(kpA0, kpA1, kpB0, kpB1,
                         rowbase + (uint32_t)jA, rowbase + (uint32_t)jA + HALFC,
                         rowbase + (uint32_t)jB, rowbase + (uint32_t)jB + HALFC,
                         ya0, ya1, yb0, yb1);
      uint32_t yA = take_hi ? ya1 : ya0;
      uint32_t yB = take_hi ? yb1 : yb0;
      // packed key: (bits23 << 9) | (511 - j); max -> max bits, tie -> min j
      uint32_t keyA = (yA & 0xFFFFFE00u) | (uint32_t)(511 - jA);
      uint32_t keyB = (yB & 0xFFFFFE00u) | (uint32_t)(511 - jB);
      if (c < ncA && keyA > bestA) bestA = keyA;
      if (c < ncB && keyB > bestB) bestB = keyB;
    }
    #pragma unroll
    for (int off = 32; off; off >>= 1) {
      uint32_t oA = (uint32_t)__shfl_xor((int)bestA, off);
      uint32_t oB = (uint32_t)__shfl_xor((int)bestB, off);
      if (oA > bestA) bestA = oA;
      if (oB > bestB) bestB = oB;
    }
    if (vA) {
      int idxA = (ncA > 0) ? (511 - (int)(bestA & 0x1FFu)) : hard;
      float tlA = pdA - drow[idxA] + 1.0f;
      if (tlA > 0.f) { wsum += (double)tlA; wcnt++; }
    }
    if (vB) {
      int idxB = (ncB > 0) ? (511 - (int)(bestB & 0x1FFu)) : hard;
      float tlB = pdB - drow[idxB] + 1.0f;
      if (tlB > 0.f) { wsum += (double)tlB; wcnt++; }
    }
  }

  if (lane == 0) { lsum[wave] = wsum; lcnt[wave] = wcnt; }
  __syncthreads();
  if (t == 0) {
    partials[bid] = lsum[0] + lsum[1] + lsum[2] + lsum[3];
    pcnt[bid] = (int)(lcnt[0] + lcnt[1] + lcnt[2] + lcnt[3]);
  }
}

// K3: deterministic fixed-order reduction of the 2048 block partials.
__global__ __launch_bounds__(256) void finalize_kernel(
    const double* __restrict__ partials, const int* __restrict__ pcnt,
    float* __restrict__ out) {
  __shared__ double ss[256];
  __shared__ int sc[256];
  int t = threadIdx.x;
  double s = 0.0;
  int c = 0;
  for (int k = t; k < NPART; k += 256) { s += partials[k]; c += pcnt[k]; }
  ss[t] = s; sc[t] = c;
  __syncthreads();
  for (int st = 128; st; st >>= 1) {
    if (t < st) { ss[t] += ss[t + st]; sc[t] += sc[t + st]; }
    __syncthreads();
  }
  if (t == 0) out[0] = sc[0] ? (float)(ss[0] / (double)sc[0]) : 0.0f;
}

extern "C" void kernel_launch(void* const* d_in, const int* in_sizes, int n_in,
                              void* d_out, int out_size, void* d_ws, size_t ws_size,
                              hipStream_t stream) {
  const float* emb = (const float*)d_in[0];
  const int* labels = (const int*)d_in[1];
  float* out = (float*)d_out;
  char* ws = (char*)d_ws;

  float* dist = (float*)ws;                            // 1 MB
  uint32_t* keys0 = (uint32_t*)(ws + 1048576);         // 2 KB
  uint32_t* keys1 = (uint32_t*)(ws + 1048576 + 2048);  // 2 KB
  double* partials = (double*)(ws + 1048576 + 4096);   // 16 KB
  int* pcnt = (int*)(ws + 1048576 + 4096 + 16384);     // 8 KB

  dist_kernel<<<256, 256, 0, stream>>>(emb, dist, keys0, keys1);
  triplet_kernel<<<B * SUB, 256, 0, stream>>>(dist, labels, keys0, keys1,
                                              partials, pcnt);
  finalize_kernel<<<1, 256, 0, stream>>>(partials, pcnt, out);
}

// Round 10
// 38.199 us; speedup vs baseline: 1.1276x; 1.1276x over previous
//
#include <hip/hip_runtime.h>
#include <stdint.h>

#define B 512
#define D 128
#define HALFC 131072u
#define SUB 4
#define NSLOT (SUB * 4)
#define NPART (B * SUB)

__device__ __forceinline__ uint32_t rotl32(uint32_t x, uint32_t r) {
  return (x << r) | (x >> (32u - r));
}

// Exact JAX/XLA threefry2x32 (20 rounds, key-schedule injections every 4).
__device__ __forceinline__ void threefry2x32(uint32_t k0, uint32_t k1,
                                             uint32_t x0, uint32_t x1,
                                             uint32_t& y0, uint32_t& y1) {
  uint32_t k2 = k0 ^ k1 ^ 0x1BD11BDAu;
  x0 += k0; x1 += k1;
#define TF_R(r) { x0 += x1; x1 = rotl32(x1, r); x1 ^= x0; }
  TF_R(13) TF_R(15) TF_R(26) TF_R(6)
  x0 += k1; x1 += k2 + 1u;
  TF_R(17) TF_R(29) TF_R(16) TF_R(24)
  x0 += k2; x1 += k0 + 2u;
  TF_R(13) TF_R(15) TF_R(26) TF_R(6)
  x0 += k0; x1 += k1 + 3u;
  TF_R(17) TF_R(29) TF_R(16) TF_R(24)
  x0 += k1; x1 += k2 + 4u;
  TF_R(13) TF_R(15) TF_R(26) TF_R(6)
  x0 += k2; x1 += k0 + 5u;
#undef TF_R
  y0 = x0; y1 = x1;
}

// Two independent threefry chains interleaved (ILP for the serial rounds).
__device__ __forceinline__ void threefry2x32_dual(
    uint32_t k0, uint32_t k1, uint32_t a0, uint32_t a1, uint32_t b0,
    uint32_t b1, uint32_t& ya0, uint32_t& ya1, uint32_t& yb0, uint32_t& yb1) {
  uint32_t k2 = k0 ^ k1 ^ 0x1BD11BDAu;
  a0 += k0; a1 += k1; b0 += k0; b1 += k1;
#define TF_R2(r) { a0 += a1; a1 = rotl32(a1, r); a1 ^= a0; \
                   b0 += b1; b1 = rotl32(b1, r); b1 ^= b0; }
  TF_R2(13) TF_R2(15) TF_R2(26) TF_R2(6)
  a0 += k1; a1 += k2 + 1u; b0 += k1; b1 += k2 + 1u;
  TF_R2(17) TF_R2(29) TF_R2(16) TF_R2(24)
  a0 += k2; a1 += k0 + 2u; b0 += k2; b1 += k0 + 2u;
  TF_R2(13) TF_R2(15) TF_R2(26) TF_R2(6)
  a0 += k0; a1 += k1 + 3u; b0 += k0; b1 += k1 + 3u;
  TF_R2(17) TF_R2(29) TF_R2(16) TF_R2(24)
  a0 += k1; a1 += k2 + 4u; b0 += k1; b1 += k2 + 4u;
  TF_R2(13) TF_R2(15) TF_R2(26) TF_R2(6)
  a0 += k2; a1 += k0 + 5u; b0 += k2; b1 += k0 + 5u;
#undef TF_R2
  ya0 = a0; ya1 = a1; yb0 = b0; yb1 = b1;
}

// K1: tiled dist "GEMM". Block (ti,tj) computes a 32x32 tile of dist from two
// coalesced-staged 32x128 LDS panels (fused sq). Block 0 also computes the
// 512 anchor keys.
__global__ __launch_bounds__(256) void dist_kernel(
    const float* __restrict__ emb, float* __restrict__ dist,
    uint32_t* __restrict__ keys0, uint32_t* __restrict__ keys1) {
  __shared__ float As[32][132];  // pad 132: bank = (4r + k) % 32, conflict-free
  __shared__ float Bs[32][132];
  __shared__ float sqa[32], sqb[32];
  int bid = blockIdx.x;
  int ti = bid >> 4, tj = bid & 15;
  int t = threadIdx.x;

  // coalesced stage: 32 rows x 128 floats = 1024 float4 per panel
  const float4* ga = reinterpret_cast<const float4*>(emb + (size_t)ti * 32 * D);
  const float4* gb = reinterpret_cast<const float4*>(emb + (size_t)tj * 32 * D);
  #pragma unroll
  for (int k = 0; k < 4; ++k) {
    int idx = t + k * 256;   // float4 index 0..1023
    int r = idx >> 5;        // 32 float4 per row
    int c4 = idx & 31;
    *reinterpret_cast<float4*>(&As[r][c4 * 4]) = ga[idx];
    *reinterpret_cast<float4*>(&Bs[r][c4 * 4]) = gb[idx];
  }
  __syncthreads();

  // fused sq: 64 rows (32 A + 32 B), 4 threads/row of 32 floats each
  {
    int row = t >> 2, seg = t & 3;
    const float* src = (row < 32) ? &As[row][seg * 32] : &Bs[row - 32][seg * 32];
    float s = 0.f;
    #pragma unroll
    for (int m = 0; m < 32; ++m) { float v = src[m]; s += v * v; }
    s += __shfl_xor(s, 1);
    s += __shfl_xor(s, 2);
    if (seg == 0) { if (row < 32) sqa[row] = s; else sqb[row - 32] = s; }
  }

  // dots: thread (r = t>>3, g = t&7) computes cols c = g + 8j, j=0..3
  int r = t >> 3, g = t & 7;
  const float4* A4 = reinterpret_cast<const float4*>(&As[r][0]);
  const float4* B0 = reinterpret_cast<const float4*>(&Bs[g][0]);
  const float4* B1 = reinterpret_cast<const float4*>(&Bs[g + 8][0]);
  const float4* B2 = reinterpret_cast<const float4*>(&Bs[g + 16][0]);
  const float4* B3 = reinterpret_cast<const float4*>(&Bs[g + 24][0]);
  float acc0 = 0.f, acc1 = 0.f, acc2 = 0.f, acc3 = 0.f;
  #pragma unroll 8
  for (int k4 = 0; k4 < 32; ++k4) {
    float4 a = A4[k4];
    float4 b0 = B0[k4], b1 = B1[k4], b2 = B2[k4], b3 = B3[k4];
    acc0 += a.x * b0.x + a.y * b0.y + a.z * b0.z + a.w * b0.w;
    acc1 += a.x * b1.x + a.y * b1.y + a.z * b1.z + a.w * b1.w;
    acc2 += a.x * b2.x + a.y * b2.y + a.z * b2.z + a.w * b2.w;
    acc3 += a.x * b3.x + a.y * b3.y + a.z * b3.z + a.w * b3.w;
  }
  __syncthreads();  // sqa/sqb ready
  float sa = sqa[r];
  float* drow = dist + (size_t)(ti * 32 + r) * B + tj * 32;
  drow[g]      = sqrtf(fmaxf(sa + sqb[g]      - 2.f * acc0, 0.f));
  drow[g + 8]  = sqrtf(fmaxf(sa + sqb[g + 8]  - 2.f * acc1, 0.f));
  drow[g + 16] = sqrtf(fmaxf(sa + sqb[g + 16] - 2.f * acc2, 0.f));
  drow[g + 24] = sqrtf(fmaxf(sa + sqb[g + 24] - 2.f * acc3, 0.f));

  // block 0 tail: anchor keys
  // keys[p] from split(key(42), 512): out[q] = q<512 ? y0(q,q+512) : y1(q-512,q)
  if (bid == 0) {
    #pragma unroll
    for (int pp = 0; pp < 2; ++pp) {
      int p = t + pp * 256;
      uint32_t i0 = 2u * (uint32_t)p, i1 = i0 + 1u;
      uint32_t a0, a1, b0, b1;
      if (p < 256) {
        threefry2x32(0u, 42u, i0, i0 + 512u, a0, a1);
        threefry2x32(0u, 42u, i1, i1 + 512u, b0, b1);
        keys0[p] = a0; keys1[p] = b0;
      } else {
        threefry2x32(0u, 42u, i0 - 512u, i0, a0, a1);
        threefry2x32(0u, 42u, i1 - 512u, i1, b0, b1);
        keys0[p] = a1; keys1[p] = b1;
      }
    }
  }
}

// K2 (row-major): block = (row i, sub). drow + ALL KEYS staged once in LDS;
// dd8m (sentinel-masked) / hard-argmin row-invariant in registers. Per anchor:
// compaction + threefry drain (dual bulk, single <=64 tail) + packed-u32 lex
// argmax (bits desc, j asc). Per-block partials write (no contended atomics).
__global__ __launch_bounds__(256) void triplet_kernel(
    const float* __restrict__ dist, const int* __restrict__ labels,
    const uint32_t* __restrict__ keys0, const uint32_t* __restrict__ keys1,
    double* __restrict__ partials, int* __restrict__ pcnt) {
  __shared__ float drow[B];
  __shared__ unsigned short slab[B];
  __shared__ uint2 skeys[B];
  __shared__ unsigned short list_sh[B];
  __shared__ unsigned short cand[4][B];
  __shared__ int nlist_sh;
  __shared__ double lsum[4];
  __shared__ unsigned int lcnt[4];

  int bid = blockIdx.x;
  int i = bid >> 2;  // SUB = 4
  int sub = bid & 3;
  int t = threadIdx.x;
  slab[t] = (unsigned short)labels[t];
  slab[t + 256] = (unsigned short)labels[t + 256];
  const float* __restrict__ dg = dist + (size_t)i * B;
  drow[t] = dg[t];
  drow[t + 256] = dg[t + 256];
  skeys[t] = make_uint2(keys0[t], keys1[t]);
  skeys[t + 256] = make_uint2(keys0[t + 256], keys1[t + 256]);
  __syncthreads();

  int wave = t >> 6, lane = t & 63;
  unsigned long long lmask_lt = (1ull << lane) - 1ull;
  unsigned short lab_i = slab[i];

  // wave 0: ascending list of same-label anchors p (includes i; skipped later)
  if (wave == 0) {
    int n = 0;
    #pragma unroll
    for (int c = 0; c < 8; ++c) {
      int r = c * 64 + lane;
      bool v = (slab[r] == lab_i);
      unsigned long long mk = __ballot(v);
      if (v) list_sh[n + __popcll(mk & lmask_lt)] = (unsigned short)r;
      n += __popcll(mk);
    }
    if (lane == 0) nlist_sh = (n == B) ? 0 : n;  // n==B -> no negatives
  }

  // row-invariant per-lane data: sentinel-masked distances + hard argmin.
  // dd8m[jc] = dist if negative-label else -3e38 (fails any (pd, pd+1) window)
  float dd8m[8];
  unsigned long long hkey = ~0ull;
  #pragma unroll
  for (int jc = 0; jc < 8; ++jc) {
    int j = jc * 64 + lane;
    float dv = drow[j];
    bool neg = (slab[j] != lab_i);
    dd8m[jc] = neg ? dv : -3.0e38f;
    if (neg) {
      unsigned long long k =
          (((unsigned long long)__float_as_uint(dv)) << 9) | (unsigned)j;
      if (k < hkey) hkey = k;
    }
  }
  #pragma unroll
  for (int off = 32; off; off >>= 1) {
    unsigned long long o = __shfl_xor(hkey, off);
    if (o < hkey) hkey = o;
  }
  int hard = (int)(hkey & 0x1FFu);  // valid whenever any negative exists
  uint32_t rowbase = (uint32_t)((i & 255) * B);
  bool take_hi = (i >= 256);
  __syncthreads();  // list_sh / nlist_sh ready

  int nlist = nlist_sh;
  unsigned short* wcand = cand[wave];
  double wsum = 0.0;
  unsigned int wcnt = 0;

  for (int k = sub * 4 + wave; k < nlist; k += NSLOT) {
    int p = list_sh[k];
    if (p == i) continue;
    p = __builtin_amdgcn_readfirstlane(p);  // wave-uniform
    uint2 kp = skeys[p];                    // single ds_read_b64, no L2 trip
    float pos_d = drow[p];
    float hiv = pos_d + 1.0f;  // margin = 1.0

    int nc = 0;
    #pragma unroll
    for (int jc = 0; jc < 8; ++jc) {
      float dd = dd8m[jc];
      bool m = (dd > pos_d) && (dd < hiv);  // sentinel folds the label test
      unsigned long long mk = __ballot(m);
      if (m) wcand[nc + __popcll(mk & lmask_lt)] =
          (unsigned short)(jc * 64 + lane);
      nc += __popcll(mk);
    }

    int idx;
    if (nc > 0) {
      // packed key: (bits23 << 9) | (511 - j); max -> max bits, tie -> min j
      uint32_t best = 0u;
      int ndual = nc >> 7;  // full 128-candidate dual chunks (wave-uniform)
      int c = lane;
      for (int it = 0; it < ndual; ++it, c += 128) {
        int j1 = wcand[c];
        int j2 = wcand[c + 64];
        uint32_t ya0, ya1, yb0, yb1;
        threefry2x32_dual(kp.x, kp.y,
                          rowbase + (uint32_t)j1, rowbase + (uint32_t)j1 + HALFC,
                          rowbase + (uint32_t)j2, rowbase + (uint32_t)j2 + HALFC,
                          ya0, ya1, yb0, yb1);
        uint32_t key1 = ((take_hi ? ya1 : ya0) & 0xFFFFFE00u) |
                        (uint32_t)(511 - j1);
        uint32_t key2 = ((take_hi ? yb1 : yb0) & 0xFFFFFE00u) |
                        (uint32_t)(511 - j2);
        if (key1 > best) best = key1;
        if (key2 > best) best = key2;
      }
      int rem = nc & 127;
      if (rem > 64) {
        // one more dual; second chunk partially masked
        int j1 = wcand[c];          // c < nc for lanes < rem (>=64), stale ok
        int j2 = wcand[c + 64];     // in-bounds (<512), masked below
        uint32_t ya0, ya1, yb0, yb1;
        threefry2x32_dual(kp.x, kp.y,
                          rowbase + (uint32_t)j1, rowbase + (uint32_t)j1 + HALFC,
                          rowbase + (uint32_t)j2, rowbase + (uint32_t)j2 + HALFC,
                          ya0, ya1, yb0, yb1);
        uint32_t key1 = ((take_hi ? ya1 : ya0) & 0xFFFFFE00u) |
                        (uint32_t)(511 - j1);
        uint32_t key2 = ((take_hi ? yb1 : yb0) & 0xFFFFFE00u) |
                        (uint32_t)(511 - j2);
        if (c < nc && key1 > best) best = key1;
        if (c + 64 < nc && key2 > best) best = key2;
      } else if (rem > 0) {
        // single-chain tail (<=64 candidates): half the op cost of a dual
        if (c < nc) {
          int j = wcand[c];
          uint32_t y0, y1;
          threefry2x32(kp.x, kp.y, rowbase + (uint32_t)j,
                       rowbase + (uint32_t)j + HALFC, y0, y1);
          uint32_t key1 = ((take_hi ? y1 : y0) & 0xFFFFFE00u) |
                          (uint32_t)(511 - j);
          if (key1 > best) best = key1;
        }
      }
      #pragma unroll
      for (int off = 32; off; off >>= 1) {
        uint32_t ob = (uint32_t)__shfl_xor((int)best, off);
        if (ob > best) best = ob;
      }
      idx = 511 - (int)(best & 0x1FFu);
    } else {
      idx = hard;
    }
    float neg_d = drow[idx];
    float tl = pos_d - neg_d + 1.0f;
    if (tl > 0.f) { wsum += (double)tl; wcnt++; }
  }

  if (lane == 0) { lsum[wave] = wsum; lcnt[wave] = wcnt; }
  __syncthreads();
  if (t == 0) {
    partials[bid] = lsum[0] + lsum[1] + lsum[2] + lsum[3];
    pcnt[bid] = (int)(lcnt[0] + lcnt[1] + lcnt[2] + lcnt[3]);
  }
}

// K3: deterministic fixed-order reduction of the 2048 block partials.
__global__ __launch_bounds__(256) void finalize_kernel(
    const double* __restrict__ partials, const int* __restrict__ pcnt,
    float* __restrict__ out) {
  __shared__ double ss[256];
  __shared__ int sc[256];
  int t = threadIdx.x;
  double s = 0.0;
  int c = 0;
  for (int k = t; k < NPART; k += 256) { s += partials[k]; c += pcnt[k]; }
  ss[t] = s; sc[t] = c;
  __syncthreads();
  for (int st = 128; st; st >>= 1) {
    if (t < st) { ss[t] += ss[t + st]; sc[t] += sc[t + st]; }
    __syncthreads();
  }
  if (t == 0) out[0] = sc[0] ? (float)(ss[0] / (double)sc[0]) : 0.0f;
}

extern "C" void kernel_launch(void* const* d_in, const int* in_sizes, int n_in,
                              void* d_out, int out_size, void* d_ws, size_t ws_size,
                              hipStream_t stream) {
  const float* emb = (const float*)d_in[0];
  const int* labels = (const int*)d_in[1];
  float* out = (float*)d_out;
  char* ws = (char*)d_ws;

  float* dist = (float*)ws;                            // 1 MB
  uint32_t* keys0 = (uint32_t*)(ws + 1048576);         // 2 KB
  uint32_t* keys1 = (uint32_t*)(ws + 1048576 + 2048);  // 2 KB
  double* partials = (double*)(ws + 1048576 + 4096);   // 16 KB
  int* pcnt = (int*)(ws + 1048576 + 4096 + 16384);     // 8 KB

  dist_kernel<<<256, 256, 0, stream>>>(emb, dist, keys0, keys1);
  triplet_kernel<<<B * SUB, 256, 0, stream>>>(dist, labels, keys0, keys1,
                                              partials, pcnt);
  finalize_kernel<<<1, 256, 0, stream>>>(partials, pcnt, out);
}

// Round 11
// 37.177 us; speedup vs baseline: 1.1586x; 1.0275x over previous
//
#include <hip/hip_runtime.h>
#include <stdint.h>

#define B 512
#define D 128
#define HALFC 131072u
#define SUB 2
#define NSLOT (SUB * 8)   /* 2 subs x 8 waves = 16 anchor slots per row */
#define NPART (B * SUB)

__device__ __forceinline__ uint32_t rotl32(uint32_t x, uint32_t r) {
  return (x << r) | (x >> (32u - r));
}

// Exact JAX/XLA threefry2x32 (20 rounds, key-schedule injections every 4).
__device__ __forceinline__ void threefry2x32(uint32_t k0, uint32_t k1,
                                             uint32_t x0, uint32_t x1,
                                             uint32_t& y0, uint32_t& y1) {
  uint32_t k2 = k0 ^ k1 ^ 0x1BD11BDAu;
  x0 += k0; x1 += k1;
#define TF_R(r) { x0 += x1; x1 = rotl32(x1, r); x1 ^= x0; }
  TF_R(13) TF_R(15) TF_R(26) TF_R(6)
  x0 += k1; x1 += k2 + 1u;
  TF_R(17) TF_R(29) TF_R(16) TF_R(24)
  x0 += k2; x1 += k0 + 2u;
  TF_R(13) TF_R(15) TF_R(26) TF_R(6)
  x0 += k0; x1 += k1 + 3u;
  TF_R(17) TF_R(29) TF_R(16) TF_R(24)
  x0 += k1; x1 += k2 + 4u;
  TF_R(13) TF_R(15) TF_R(26) TF_R(6)
  x0 += k2; x1 += k0 + 5u;
#undef TF_R
  y0 = x0; y1 = x1;
}

// Two independent threefry chains interleaved (ILP for the serial rounds).
__device__ __forceinline__ void threefry2x32_dual(
    uint32_t k0, uint32_t k1, uint32_t a0, uint32_t a1, uint32_t b0,
    uint32_t b1, uint32_t& ya0, uint32_t& ya1, uint32_t& yb0, uint32_t& yb1) {
  uint32_t k2 = k0 ^ k1 ^ 0x1BD11BDAu;
  a0 += k0; a1 += k1; b0 += k0; b1 += k1;
#define TF_R2(r) { a0 += a1; a1 = rotl32(a1, r); a1 ^= a0; \
                   b0 += b1; b1 = rotl32(b1, r); b1 ^= b0; }
  TF_R2(13) TF_R2(15) TF_R2(26) TF_R2(6)
  a0 += k1; a1 += k2 + 1u; b0 += k1; b1 += k2 + 1u;
  TF_R2(17) TF_R2(29) TF_R2(16) TF_R2(24)
  a0 += k2; a1 += k0 + 2u; b0 += k2; b1 += k0 + 2u;
  TF_R2(13) TF_R2(15) TF_R2(26) TF_R2(6)
  a0 += k0; a1 += k1 + 3u; b0 += k0; b1 += k1 + 3u;
  TF_R2(17) TF_R2(29) TF_R2(16) TF_R2(24)
  a0 += k1; a1 += k2 + 4u; b0 += k1; b1 += k2 + 4u;
  TF_R2(13) TF_R2(15) TF_R2(26) TF_R2(6)
  a0 += k2; a1 += k0 + 5u; b0 += k2; b1 += k0 + 5u;
#undef TF_R2
  ya0 = a0; ya1 = a1; yb0 = b0; yb1 = b1;
}

// 64-lane max-reduce via DPP (rocPRIM pattern): row_shr 1/2/4/8 then
// row_bcast 15/31; identity-0 fill (keys are nonnegative); result in lane 63.
__device__ __forceinline__ uint32_t dpp_max_all(uint32_t x) {
  uint32_t t;
#define DPP_STEP(ctrl) \
  t = (uint32_t)__builtin_amdgcn_update_dpp(0, (int)x, ctrl, 0xf, 0xf, true); \
  x = (t > x) ? t : x;
  DPP_STEP(0x111)  // row_shr:1
  DPP_STEP(0x112)  // row_shr:2
  DPP_STEP(0x114)  // row_shr:4
  DPP_STEP(0x118)  // row_shr:8
  DPP_STEP(0x142)  // row_bcast:15
  DPP_STEP(0x143)  // row_bcast:31
#undef DPP_STEP
  return (uint32_t)__builtin_amdgcn_readlane((int)x, 63);
}

// K1: tiled dist "GEMM". Block (ti,tj) computes a 32x32 tile of dist from two
// coalesced-staged 32x128 LDS panels (fused sq). Block 0 also computes the
// 512 anchor keys.
__global__ __launch_bounds__(256) void dist_kernel(
    const float* __restrict__ emb, float* __restrict__ dist,
    uint32_t* __restrict__ keys0, uint32_t* __restrict__ keys1) {
  __shared__ float As[32][132];  // pad 132: bank = (4r + k) % 32, conflict-free
  __shared__ float Bs[32][132];
  __shared__ float sqa[32], sqb[32];
  int bid = blockIdx.x;
  int ti = bid >> 4, tj = bid & 15;
  int t = threadIdx.x;

  // coalesced stage: 32 rows x 128 floats = 1024 float4 per panel
  const float4* ga = reinterpret_cast<const float4*>(emb + (size_t)ti * 32 * D);
  const float4* gb = reinterpret_cast<const float4*>(emb + (size_t)tj * 32 * D);
  #pragma unroll
  for (int k = 0; k < 4; ++k) {
    int idx = t + k * 256;   // float4 index 0..1023
    int r = idx >> 5;        // 32 float4 per row
    int c4 = idx & 31;
    *reinterpret_cast<float4*>(&As[r][c4 * 4]) = ga[idx];
    *reinterpret_cast<float4*>(&Bs[r][c4 * 4]) = gb[idx];
  }
  __syncthreads();

  // fused sq: 64 rows (32 A + 32 B), 4 threads/row of 32 floats each
  {
    int row = t >> 2, seg = t & 3;
    const float* src = (row < 32) ? &As[row][seg * 32] : &Bs[row - 32][seg * 32];
    float s = 0.f;
    #pragma unroll
    for (int m = 0; m < 32; ++m) { float v = src[m]; s += v * v; }
    s += __shfl_xor(s, 1);
    s += __shfl_xor(s, 2);
    if (seg == 0) { if (row < 32) sqa[row] = s; else sqb[row - 32] = s; }
  }

  // dots: thread (r = t>>3, g = t&7) computes cols c = g + 8j, j=0..3
  int r = t >> 3, g = t & 7;
  const float4* A4 = reinterpret_cast<const float4*>(&As[r][0]);
  const float4* B0 = reinterpret_cast<const float4*>(&Bs[g][0]);
  const float4* B1 = reinterpret_cast<const float4*>(&Bs[g + 8][0]);
  const float4* B2 = reinterpret_cast<const float4*>(&Bs[g + 16][0]);
  const float4* B3 = reinterpret_cast<const float4*>(&Bs[g + 24][0]);
  float acc0 = 0.f, acc1 = 0.f, acc2 = 0.f, acc3 = 0.f;
  #pragma unroll 8
  for (int k4 = 0; k4 < 32; ++k4) {
    float4 a = A4[k4];
    float4 b0 = B0[k4], b1 = B1[k4], b2 = B2[k4], b3 = B3[k4];
    acc0 += a.x * b0.x + a.y * b0.y + a.z * b0.z + a.w * b0.w;
    acc1 += a.x * b1.x + a.y * b1.y + a.z * b1.z + a.w * b1.w;
    acc2 += a.x * b2.x + a.y * b2.y + a.z * b2.z + a.w * b2.w;
    acc3 += a.x * b3.x + a.y * b3.y + a.z * b3.z + a.w * b3.w;
  }
  __syncthreads();  // sqa/sqb ready
  float sa = sqa[r];
  float* drow = dist + (size_t)(ti * 32 + r) * B + tj * 32;
  drow[g]      = sqrtf(fmaxf(sa + sqb[g]      - 2.f * acc0, 0.f));
  drow[g + 8]  = sqrtf(fmaxf(sa + sqb[g + 8]  - 2.f * acc1, 0.f));
  drow[g + 16] = sqrtf(fmaxf(sa + sqb[g + 16] - 2.f * acc2, 0.f));
  drow[g + 24] = sqrtf(fmaxf(sa + sqb[g + 24] - 2.f * acc3, 0.f));

  // block 0 tail: anchor keys
  // keys[p] from split(key(42), 512): out[q] = q<512 ? y0(q,q+512) : y1(q-512,q)
  if (bid == 0) {
    #pragma unroll
    for (int pp = 0; pp < 2; ++pp) {
      int p = t + pp * 256;
      uint32_t i0 = 2u * (uint32_t)p, i1 = i0 + 1u;
      uint32_t a0, a1, b0, b1;
      if (p < 256) {
        threefry2x32(0u, 42u, i0, i0 + 512u, a0, a1);
        threefry2x32(0u, 42u, i1, i1 + 512u, b0, b1);
        keys0[p] = a0; keys1[p] = b0;
      } else {
        threefry2x32(0u, 42u, i0 - 512u, i0, a0, a1);
        threefry2x32(0u, 42u, i1 - 512u, i1, b0, b1);
        keys0[p] = a1; keys1[p] = b1;
      }
    }
  }
}

// K2 (row-major): 512-thread blocks (8 waves), SUB=2 per row. drow + keys +
// labels staged once in LDS, shared by 8 waves. Anchor loop software-
// pipelined (prefetch next anchor's key/pos_d before current drain);
// self/invalid anchors via pos_d=-2 sentinel (branchless). Per-anchor
// argmax reduce via DPP (no ds_bpermute chain).
__global__ __launch_bounds__(512) void triplet_kernel(
    const float* __restrict__ dist, const int* __restrict__ labels,
    const uint32_t* __restrict__ keys0, const uint32_t* __restrict__ keys1,
    double* __restrict__ partials, int* __restrict__ pcnt) {
  __shared__ float drow[B];
  __shared__ unsigned short slab[B];
  __shared__ uint2 skeys[B];
  __shared__ unsigned short list_sh[B];
  __shared__ unsigned short cand[8][B];
  __shared__ int nlist_sh;
  __shared__ double lsum[8];
  __shared__ unsigned int lcnt[8];

  int bid = blockIdx.x;
  int i = bid >> 1;  // SUB = 2
  int sub = bid & 1;
  int t = threadIdx.x;
  slab[t] = (unsigned short)labels[t];
  drow[t] = dist[(size_t)i * B + t];
  skeys[t] = make_uint2(keys0[t], keys1[t]);
  __syncthreads();

  int wave = t >> 6, lane = t & 63;
  unsigned long long lmask_lt = (1ull << lane) - 1ull;
  unsigned short lab_i = slab[i];

  // wave 0: ascending list of same-label anchors p (includes i; sentineled)
  if (wave == 0) {
    int n = 0;
    #pragma unroll
    for (int c = 0; c < 8; ++c) {
      int r = c * 64 + lane;
      bool v = (slab[r] == lab_i);
      unsigned long long mk = __ballot(v);
      if (v) list_sh[n + __popcll(mk & lmask_lt)] = (unsigned short)r;
      n += __popcll(mk);
    }
    if (lane == 0) nlist_sh = (n == B) ? 0 : n;  // n==B -> no negatives
  }

  // row-invariant per-lane data: sentinel-masked distances + hard argmin.
  float dd8m[8];
  unsigned long long hkey = ~0ull;
  #pragma unroll
  for (int jc = 0; jc < 8; ++jc) {
    int j = jc * 64 + lane;
    float dv = drow[j];
    bool neg = (slab[j] != lab_i);
    dd8m[jc] = neg ? dv : -3.0e38f;
    if (neg) {
      unsigned long long k =
          (((unsigned long long)__float_as_uint(dv)) << 9) | (unsigned)j;
      if (k < hkey) hkey = k;
    }
  }
  #pragma unroll
  for (int off = 32; off; off >>= 1) {
    unsigned long long o = __shfl_xor(hkey, off);
    if (o < hkey) hkey = o;
  }
  int hard = (int)(hkey & 0x1FFu);  // valid whenever any negative exists
  uint32_t rowbase = (uint32_t)((i & 255) * B);
  bool take_hi = (i >= 256);
  __syncthreads();  // list_sh / nlist_sh ready

  int nlist = nlist_sh;
  unsigned short* wcand = cand[wave];
  double wsum = 0.0;
  unsigned int wcnt = 0;

#define LOAD_ANCHOR(KK, KP, PD) { \
    int p_ = list_sh[KK]; \
    p_ = __builtin_amdgcn_readfirstlane(p_); \
    KP = skeys[p_]; \
    PD = (p_ == i) ? -2.0f : drow[p_]; /* sentinel: window (-2,-1) empty */ }

  int k = sub * 8 + wave;
  uint2 kpN; float pdN;
  if (k < nlist) LOAD_ANCHOR(k, kpN, pdN);

  while (k < nlist) {
    uint2 kp = kpN;
    float pos_d = pdN;
    int kn = k + NSLOT;
    if (kn < nlist) LOAD_ANCHOR(kn, kpN, pdN);  // prefetch next anchor
    float hiv = pos_d + 1.0f;  // margin = 1.0

    int nc = 0;
    #pragma unroll
    for (int jc = 0; jc < 8; ++jc) {
      float dd = dd8m[jc];
      bool m = (dd > pos_d) && (dd < hiv);  // sentinel folds the label test
      unsigned long long mk = __ballot(m);
      if (m) wcand[nc + __popcll(mk & lmask_lt)] =
          (unsigned short)(jc * 64 + lane);
      nc += __popcll(mk);
    }

    float tl = -1.0f;
    if (nc > 0) {
      // packed key: (bits23 << 9) | (511 - j); max -> max bits, tie -> min j
      uint32_t best = 0u;
      int ndual = nc >> 7;  // full 128-candidate dual chunks (wave-uniform)
      int c = lane;
      for (int it = 0; it < ndual; ++it, c += 128) {
        int j1 = wcand[c];
        int j2 = wcand[c + 64];
        uint32_t ya0, ya1, yb0, yb1;
        threefry2x32_dual(kp.x, kp.y,
                          rowbase + (uint32_t)j1, rowbase + (uint32_t)j1 + HALFC,
                          rowbase + (uint32_t)j2, rowbase + (uint32_t)j2 + HALFC,
                          ya0, ya1, yb0, yb1);
        uint32_t key1 = ((take_hi ? ya1 : ya0) & 0xFFFFFE00u) |
                        (uint32_t)(511 - j1);
        uint32_t key2 = ((take_hi ? yb1 : yb0) & 0xFFFFFE00u) |
                        (uint32_t)(511 - j2);
        if (key1 > best) best = key1;
        if (key2 > best) best = key2;
      }
      int rem = nc & 127;
      if (rem > 64) {
        int j1 = wcand[c];
        int j2 = wcand[c + 64];
        uint32_t ya0, ya1, yb0, yb1;
        threefry2x32_dual(kp.x, kp.y,
                          rowbase + (uint32_t)j1, rowbase + (uint32_t)j1 + HALFC,
                          rowbase + (uint32_t)j2, rowbase + (uint32_t)j2 + HALFC,
                          ya0, ya1, yb0, yb1);
        uint32_t key1 = ((take_hi ? ya1 : ya0) & 0xFFFFFE00u) |
                        (uint32_t)(511 - j1);
        uint32_t key2 = ((take_hi ? yb1 : yb0) & 0xFFFFFE00u) |
                        (uint32_t)(511 - j2);
        if (c < nc && key1 > best) best = key1;
        if (c + 64 < nc && key2 > best) best = key2;
      } else if (rem > 0) {
        if (c < nc) {
          int j = wcand[c];
          uint32_t y0, y1;
          threefry2x32(kp.x, kp.y, rowbase + (uint32_t)j,
                       rowbase + (uint32_t)j + HALFC, y0, y1);
          uint32_t key1 = ((take_hi ? y1 : y0) & 0xFFFFFE00u) |
                          (uint32_t)(511 - j);
          if (key1 > best) best = key1;
        }
      }
      best = dpp_max_all(best);  // 12 VALU ops vs 6 serial ds_bpermute
      int idx = 511 - (int)(best & 0x1FFu);
      tl = pos_d - drow[idx] + 1.0f;
    } else {
      tl = pos_d - drow[hard] + 1.0f;  // sentinel pos_d=-2 -> tl<0, dropped
    }
    if (tl > 0.f) { wsum += (double)tl; wcnt++; }
    k = kn;
  }
#undef LOAD_ANCHOR

  if (lane == 0) { lsum[wave] = wsum; lcnt[wave] = wcnt; }
  __syncthreads();
  if (t == 0) {
    double s = 0.0;
    unsigned int c = 0;
    #pragma unroll
    for (int w = 0; w < 8; ++w) { s += lsum[w]; c += lcnt[w]; }
    partials[bid] = s;
    pcnt[bid] = (int)c;
  }
}

// K3: deterministic fixed-order reduction of the 1024 block partials.
__global__ __launch_bounds__(256) void finalize_kernel(
    const double* __restrict__ partials, const int* __restrict__ pcnt,
    float* __restrict__ out) {
  __shared__ double ss[256];
  __shared__ int sc[256];
  int t = threadIdx.x;
  double s = 0.0;
  int c = 0;
  for (int k = t; k < NPART; k += 256) { s += partials[k]; c += pcnt[k]; }
  ss[t] = s; sc[t] = c;
  __syncthreads();
  for (int st = 128; st; st >>= 1) {
    if (t < st) { ss[t] += ss[t + st]; sc[t] += sc[t + st]; }
    __syncthreads();
  }
  if (t == 0) out[0] = sc[0] ? (float)(ss[0] / (double)sc[0]) : 0.0f;
}

extern "C" void kernel_launch(void* const* d_in, const int* in_sizes, int n_in,
                              void* d_out, int out_size, void* d_ws, size_t ws_size,
                              hipStream_t stream) {
  const float* emb = (const float*)d_in[0];
  const int* labels = (const int*)d_in[1];
  float* out = (float*)d_out;
  char* ws = (char*)d_ws;

  float* dist = (float*)ws;                            // 1 MB
  uint32_t* keys0 = (uint32_t*)(ws + 1048576);         // 2 KB
  uint32_t* keys1 = (uint32_t*)(ws + 1048576 + 2048);  // 2 KB
  double* partials = (double*)(ws + 1048576 + 4096);   // 8 KB
  int* pcnt = (int*)(ws + 1048576 + 4096 + 8192);      // 4 KB

  dist_kernel<<<256, 256, 0, stream>>>(emb, dist, keys0, keys1);
  triplet_kernel<<<B * SUB, 512, 0, stream>>>(dist, labels, keys0, keys1,
                                              partials, pcnt);
  finalize_kernel<<<1, 256, 0, stream>>>(partials, pcnt, out);
}

// Round 12
// 36.886 us; speedup vs baseline: 1.1677x; 1.0079x over previous
//
#include <hip/hip_runtime.h>
#include <stdint.h>

#define B 512
#define D 128
#define HALFC 131072u
#define SUB 2
#define NSLOT (SUB * 8)   /* 2 subs x 8 waves = 16 anchor slots per row */
#define NPART (B * SUB)

__device__ __forceinline__ uint32_t rotl32(uint32_t x, uint32_t r) {
  return (x << r) | (x >> (32u - r));
}

// Exact JAX/XLA threefry2x32 (20 rounds, key-schedule injections every 4).
__device__ __forceinline__ void threefry2x32(uint32_t k0, uint32_t k1,
                                             uint32_t x0, uint32_t x1,
                                             uint32_t& y0, uint32_t& y1) {
  uint32_t k2 = k0 ^ k1 ^ 0x1BD11BDAu;
  x0 += k0; x1 += k1;
#define TF_R(r) { x0 += x1; x1 = rotl32(x1, r); x1 ^= x0; }
  TF_R(13) TF_R(15) TF_R(26) TF_R(6)
  x0 += k1; x1 += k2 + 1u;
  TF_R(17) TF_R(29) TF_R(16) TF_R(24)
  x0 += k2; x1 += k0 + 2u;
  TF_R(13) TF_R(15) TF_R(26) TF_R(6)
  x0 += k0; x1 += k1 + 3u;
  TF_R(17) TF_R(29) TF_R(16) TF_R(24)
  x0 += k1; x1 += k2 + 4u;
  TF_R(13) TF_R(15) TF_R(26) TF_R(6)
  x0 += k2; x1 += k0 + 5u;
#undef TF_R
  y0 = x0; y1 = x1;
}

// N independent threefry chains, fully unrolled in registers (N compile-time
// => all array indices constant, no scratch). In-place: results in x0/x1.
template <int N>
__device__ __forceinline__ void tf_multi(uint32_t k0, uint32_t k1,
                                         uint32_t (&x0)[N], uint32_t (&x1)[N]) {
  uint32_t k2 = k0 ^ k1 ^ 0x1BD11BDAu;
#pragma unroll
  for (int q = 0; q < N; ++q) { x0[q] += k0; x1[q] += k1; }
#define TFM_R(r) \
  _Pragma("unroll") for (int q = 0; q < N; ++q) { \
    x0[q] += x1[q]; x1[q] = rotl32(x1[q], r); x1[q] ^= x0[q]; }
#define TFM_INJ(a, b, c) \
  _Pragma("unroll") for (int q = 0; q < N; ++q) { x0[q] += a; x1[q] += b + c; }
  TFM_R(13) TFM_R(15) TFM_R(26) TFM_R(6)
  TFM_INJ(k1, k2, 1u)
  TFM_R(17) TFM_R(29) TFM_R(16) TFM_R(24)
  TFM_INJ(k2, k0, 2u)
  TFM_R(13) TFM_R(15) TFM_R(26) TFM_R(6)
  TFM_INJ(k0, k1, 3u)
  TFM_R(17) TFM_R(29) TFM_R(16) TFM_R(24)
  TFM_INJ(k1, k2, 4u)
  TFM_R(13) TFM_R(15) TFM_R(26) TFM_R(6)
  TFM_INJ(k2, k0, 5u)
#undef TFM_R
#undef TFM_INJ
}

// 64-lane max-reduce via DPP (rocPRIM pattern): row_shr 1/2/4/8 then
// row_bcast 15/31; identity-0 fill (keys are nonnegative); result in lane 63.
__device__ __forceinline__ uint32_t dpp_max_all(uint32_t x) {
  uint32_t t;
#define DPP_STEP(ctrl) \
  t = (uint32_t)__builtin_amdgcn_update_dpp(0, (int)x, ctrl, 0xf, 0xf, true); \
  x = (t > x) ? t : x;
  DPP_STEP(0x111)  // row_shr:1
  DPP_STEP(0x112)  // row_shr:2
  DPP_STEP(0x114)  // row_shr:4
  DPP_STEP(0x118)  // row_shr:8
  DPP_STEP(0x142)  // row_bcast:15
  DPP_STEP(0x143)  // row_bcast:31
#undef DPP_STEP
  return (uint32_t)__builtin_amdgcn_readlane((int)x, 63);
}

// K1: tiled dist "GEMM". Block (ti,tj) computes a 32x32 tile of dist from two
// coalesced-staged 32x128 LDS panels (fused sq). Block 0 also computes the
// 512 anchor keys.
__global__ __launch_bounds__(256) void dist_kernel(
    const float* __restrict__ emb, float* __restrict__ dist,
    uint32_t* __restrict__ keys0, uint32_t* __restrict__ keys1) {
  __shared__ float As[32][132];  // pad 132: bank = (4r + k) % 32, conflict-free
  __shared__ float Bs[32][132];
  __shared__ float sqa[32], sqb[32];
  int bid = blockIdx.x;
  int ti = bid >> 4, tj = bid & 15;
  int t = threadIdx.x;

  // coalesced stage: 32 rows x 128 floats = 1024 float4 per panel
  const float4* ga = reinterpret_cast<const float4*>(emb + (size_t)ti * 32 * D);
  const float4* gb = reinterpret_cast<const float4*>(emb + (size_t)tj * 32 * D);
  #pragma unroll
  for (int k = 0; k < 4; ++k) {
    int idx = t + k * 256;   // float4 index 0..1023
    int r = idx >> 5;        // 32 float4 per row
    int c4 = idx & 31;
    *reinterpret_cast<float4*>(&As[r][c4 * 4]) = ga[idx];
    *reinterpret_cast<float4*>(&Bs[r][c4 * 4]) = gb[idx];
  }
  __syncthreads();

  // fused sq: 64 rows (32 A + 32 B), 4 threads/row of 32 floats each
  {
    int row = t >> 2, seg = t & 3;
    const float* src = (row < 32) ? &As[row][seg * 32] : &Bs[row - 32][seg * 32];
    float s = 0.f;
    #pragma unroll
    for (int m = 0; m < 32; ++m) { float v = src[m]; s += v * v; }
    s += __shfl_xor(s, 1);
    s += __shfl_xor(s, 2);
    if (seg == 0) { if (row < 32) sqa[row] = s; else sqb[row - 32] = s; }
  }

  // dots: thread (r = t>>3, g = t&7) computes cols c = g + 8j, j=0..3
  int r = t >> 3, g = t & 7;
  const float4* A4 = reinterpret_cast<const float4*>(&As[r][0]);
  const float4* B0 = reinterpret_cast<const float4*>(&Bs[g][0]);
  const float4* B1 = reinterpret_cast<const float4*>(&Bs[g + 8][0]);
  const float4* B2 = reinterpret_cast<const float4*>(&Bs[g + 16][0]);
  const float4* B3 = reinterpret_cast<const float4*>(&Bs[g + 24][0]);
  float acc0 = 0.f, acc1 = 0.f, acc2 = 0.f, acc3 = 0.f;
  #pragma unroll 8
  for (int k4 = 0; k4 < 32; ++k4) {
    float4 a = A4[k4];
    float4 b0 = B0[k4], b1 = B1[k4], b2 = B2[k4], b3 = B3[k4];
    acc0 += a.x * b0.x + a.y * b0.y + a.z * b0.z + a.w * b0.w;
    acc1 += a.x * b1.x + a.y * b1.y + a.z * b1.z + a.w * b1.w;
    acc2 += a.x * b2.x + a.y * b2.y + a.z * b2.z + a.w * b2.w;
    acc3 += a.x * b3.x + a.y * b3.y + a.z * b3.z + a.w * b3.w;
  }
  __syncthreads();  // sqa/sqb ready
  float sa = sqa[r];
  float* drow = dist + (size_t)(ti * 32 + r) * B + tj * 32;
  drow[g]      = sqrtf(fmaxf(sa + sqb[g]      - 2.f * acc0, 0.f));
  drow[g + 8]  = sqrtf(fmaxf(sa + sqb[g + 8]  - 2.f * acc1, 0.f));
  drow[g + 16] = sqrtf(fmaxf(sa + sqb[g + 16] - 2.f * acc2, 0.f));
  drow[g + 24] = sqrtf(fmaxf(sa + sqb[g + 24] - 2.f * acc3, 0.f));

  // block 0 tail: anchor keys
  // keys[p] from split(key(42), 512): out[q] = q<512 ? y0(q,q+512) : y1(q-512,q)
  if (bid == 0) {
    #pragma unroll
    for (int pp = 0; pp < 2; ++pp) {
      int p = t + pp * 256;
      uint32_t i0 = 2u * (uint32_t)p, i1 = i0 + 1u;
      uint32_t a0, a1, b0, b1;
      if (p < 256) {
        threefry2x32(0u, 42u, i0, i0 + 512u, a0, a1);
        threefry2x32(0u, 42u, i1, i1 + 512u, b0, b1);
        keys0[p] = a0; keys1[p] = b0;
      } else {
        threefry2x32(0u, 42u, i0 - 512u, i0, a0, a1);
        threefry2x32(0u, 42u, i1 - 512u, i1, b0, b1);
        keys0[p] = a1; keys1[p] = b1;
      }
    }
  }
}

// K2 (row-major): 512-thread blocks (8 waves), SUB=2 per row. drow + keys +
// labels staged once in LDS. Anchor loop software-pipelined. Drain = ONE
// chain-count-matched tf_multi<ceil(nc/64)> call (1..4 chains; quad loop for
// nc>256) -> single serial 20-round latency per anchor instead of two.
__global__ __launch_bounds__(512) void triplet_kernel(
    const float* __restrict__ dist, const int* __restrict__ labels,
    const uint32_t* __restrict__ keys0, const uint32_t* __restrict__ keys1,
    double* __restrict__ partials, int* __restrict__ pcnt) {
  __shared__ float drow[B];
  __shared__ unsigned short slab[B];
  __shared__ uint2 skeys[B];
  __shared__ unsigned short list_sh[B];
  __shared__ unsigned short cand[8][B];
  __shared__ int nlist_sh;
  __shared__ double lsum[8];
  __shared__ unsigned int lcnt[8];

  int bid = blockIdx.x;
  int i = bid >> 1;  // SUB = 2
  int sub = bid & 1;
  int t = threadIdx.x;
  slab[t] = (unsigned short)labels[t];
  drow[t] = dist[(size_t)i * B + t];
  skeys[t] = make_uint2(keys0[t], keys1[t]);
  __syncthreads();

  int wave = t >> 6, lane = t & 63;
  unsigned long long lmask_lt = (1ull << lane) - 1ull;
  unsigned short lab_i = slab[i];

  // wave 0: ascending list of same-label anchors p (includes i; sentineled)
  if (wave == 0) {
    int n = 0;
    #pragma unroll
    for (int c = 0; c < 8; ++c) {
      int r = c * 64 + lane;
      bool v = (slab[r] == lab_i);
      unsigned long long mk = __ballot(v);
      if (v) list_sh[n + __popcll(mk & lmask_lt)] = (unsigned short)r;
      n += __popcll(mk);
    }
    if (lane == 0) nlist_sh = (n == B) ? 0 : n;  // n==B -> no negatives
  }

  // row-invariant per-lane data: sentinel-masked distances + hard argmin.
  float dd8m[8];
  unsigned long long hkey = ~0ull;
  #pragma unroll
  for (int jc = 0; jc < 8; ++jc) {
    int j = jc * 64 + lane;
    float dv = drow[j];
    bool neg = (slab[j] != lab_i);
    dd8m[jc] = neg ? dv : -3.0e38f;
    if (neg) {
      unsigned long long k =
          (((unsigned long long)__float_as_uint(dv)) << 9) | (unsigned)j;
      if (k < hkey) hkey = k;
    }
  }
  #pragma unroll
  for (int off = 32; off; off >>= 1) {
    unsigned long long o = __shfl_xor(hkey, off);
    if (o < hkey) hkey = o;
  }
  int hard = (int)(hkey & 0x1FFu);  // valid whenever any negative exists
  uint32_t rowbase = (uint32_t)((i & 255) * B);
  bool take_hi = (i >= 256);
  __syncthreads();  // list_sh / nlist_sh ready

  int nlist = nlist_sh;
  unsigned short* wcand = cand[wave];
  double wsum = 0.0;
  unsigned int wcnt = 0;

#define LOAD_ANCHOR(KK, KP, PD) { \
    int p_ = list_sh[KK]; \
    p_ = __builtin_amdgcn_readfirstlane(p_); \
    KP = skeys[p_]; \
    PD = (p_ == i) ? -2.0f : drow[p_]; /* sentinel: window (-2,-1) empty */ }

// One drain step of NCH chains starting at candidate index c0 (+64 per chain).
#define DRAIN(NCH) { \
    uint32_t xs0[NCH], xs1[NCH], js[NCH]; \
    _Pragma("unroll") for (int q = 0; q < NCH; ++q) { \
      int c_ = c0 + q * 64; \
      uint32_t j_ = wcand[(c_ < nc) ? c_ : 0]; \
      js[q] = j_; \
      xs0[q] = rowbase + j_; \
      xs1[q] = rowbase + j_ + HALFC; \
    } \
    tf_multi<NCH>(kp.x, kp.y, xs0, xs1); \
    _Pragma("unroll") for (int q = 0; q < NCH; ++q) { \
      int c_ = c0 + q * 64; \
      uint32_t kk = ((take_hi ? xs1[q] : xs0[q]) & 0xFFFFFE00u) | \
                    (511u - js[q]); \
      if (c_ < nc && kk > best) best = kk; \
    } }

  int k = sub * 8 + wave;
  uint2 kpN; float pdN;
  if (k < nlist) LOAD_ANCHOR(k, kpN, pdN);

  while (k < nlist) {
    uint2 kp = kpN;
    float pos_d = pdN;
    int kn = k + NSLOT;
    if (kn < nlist) LOAD_ANCHOR(kn, kpN, pdN);  // prefetch next anchor
    float hiv = pos_d + 1.0f;  // margin = 1.0

    int nc = 0;
    #pragma unroll
    for (int jc = 0; jc < 8; ++jc) {
      float dd = dd8m[jc];
      bool m = (dd > pos_d) && (dd < hiv);  // sentinel folds the label test
      unsigned long long mk = __ballot(m);
      if (m) wcand[nc + __popcll(mk & lmask_lt)] =
          (unsigned short)(jc * 64 + lane);
      nc += __popcll(mk);
    }

    float tl;
    if (nc > 0) {
      // packed key: (bits23 << 9) | (511 - j); max -> max bits, tie -> min j
      uint32_t best = 0u;
      int nch = (nc + 63) >> 6;  // chains needed (wave-uniform)
      int c0 = lane;
      while (nch > 4) { DRAIN(4); c0 += 256; nch -= 4; }
      switch (nch) {
        case 4: DRAIN(4); break;
        case 3: DRAIN(3); break;
        case 2: DRAIN(2); break;
        default: DRAIN(1); break;
      }
      best = dpp_max_all(best);
      int idx = 511 - (int)(best & 0x1FFu);
      tl = pos_d - drow[idx] + 1.0f;
    } else {
      tl = pos_d - drow[hard] + 1.0f;  // sentinel pos_d=-2 -> tl<0, dropped
    }
    if (tl > 0.f) { wsum += (double)tl; wcnt++; }
    k = kn;
  }
#undef LOAD_ANCHOR
#undef DRAIN

  if (lane == 0) { lsum[wave] = wsum; lcnt[wave] = wcnt; }
  __syncthreads();
  if (t == 0) {
    double s = 0.0;
    unsigned int c = 0;
    #pragma unroll
    for (int w = 0; w < 8; ++w) { s += lsum[w]; c += lcnt[w]; }
    partials[bid] = s;
    pcnt[bid] = (int)c;
  }
}

// K3: deterministic fixed-order reduction of the 1024 block partials.
__global__ __launch_bounds__(256) void finalize_kernel(
    const double* __restrict__ partials, const int* __restrict__ pcnt,
    float* __restrict__ out) {
  __shared__ double ss[256];
  __shared__ int sc[256];
  int t = threadIdx.x;
  double s = 0.0;
  int c = 0;
  for (int k = t; k < NPART; k += 256) { s += partials[k]; c += pcnt[k]; }
  ss[t] = s; sc[t] = c;
  __syncthreads();
  for (int st = 128; st; st >>= 1) {
    if (t < st) { ss[t] += ss[t + st]; sc[t] += sc[t + st]; }
    __syncthreads();
  }
  if (t == 0) out[0] = sc[0] ? (float)(ss[0] / (double)sc[0]) : 0.0f;
}

extern "C" void kernel_launch(void* const* d_in, const int* in_sizes, int n_in,
                              void* d_out, int out_size, void* d_ws, size_t ws_size,
                              hipStream_t stream) {
  const float* emb = (const float*)d_in[0];
  const int* labels = (const int*)d_in[1];
  float* out = (float*)d_out;
  char* ws = (char*)d_ws;

  float* dist = (float*)ws;                            // 1 MB
  uint32_t* keys0 = (uint32_t*)(ws + 1048576);         // 2 KB
  uint32_t* keys1 = (uint32_t*)(ws + 1048576 + 2048);  // 2 KB
  double* partials = (double*)(ws + 1048576 + 4096);   // 8 KB
  int* pcnt = (int*)(ws + 1048576 + 4096 + 8192);      // 4 KB

  dist_kernel<<<256, 256, 0, stream>>>(emb, dist, keys0, keys1);
  triplet_kernel<<<B * SUB, 512, 0, stream>>>(dist, labels, keys0, keys1,
                                              partials, pcnt);
  finalize_kernel<<<1, 256, 0, stream>>>(partials, pcnt, out);
}